// Round 22
// baseline (420.708 us; speedup 1.0000x reference)
//
#include <hip/hip_runtime.h>
#include <hip/hip_bf16.h>
#include <math.h>

#define LRELU(v) ((v) >= 0.f ? (v) : 0.1f * (v))
#define LOG2E 1.4426950408889634f

typedef __attribute__((ext_vector_type(8))) short short8;
typedef __attribute__((ext_vector_type(4))) float f32x4;

#define MFMA16 __builtin_amdgcn_mfma_f32_16x16x32_bf16

__device__ __forceinline__ float loadf(const float* p) { return *p; }
__device__ __forceinline__ float loadf(const __hip_bfloat16* p) { return __bfloat162float(*p); }
__device__ __forceinline__ short f2bfbits(float f) {
    __hip_bfloat16 h = __float2bfloat16(f);
    return *reinterpret_cast<short*>(&h);
}
__device__ __forceinline__ float bits2f(unsigned short u) {
    union { unsigned int i; float f; } x; x.i = ((unsigned int)u) << 16; return x.f;
}
__device__ __forceinline__ float lo2f(unsigned int v) {
    union { unsigned int i; float f; } x; x.i = v << 16; return x.f;
}
__device__ __forceinline__ float hi2f(unsigned int v) {
    union { unsigned int i; float f; } x; x.i = v & 0xFFFF0000u; return x.f;
}

// ---------------------------------------------------------------------------
// NCHW f32 -> NHWC bf16 transpose for ref+ta, + exact f32 overexposure mask.
__global__ __launch_bounds__(256) void nhwc_kernel(const float* __restrict__ ref,
                                                   const float* __restrict__ ta,
                                                   __hip_bfloat16* __restrict__ refn,
                                                   __hip_bfloat16* __restrict__ tan,
                                                   float* __restrict__ maskp,
                                                   int H, int HW) {
    __shared__ float S[2][64][67];
    const int tid = threadIdx.x;
    const int tile = blockIdx.x;
    const int b = blockIdx.y;
    const int tpr = H >> 6;
    const int y = tile / tpr;
    const int x0 = (tile - y * tpr) << 6;
    const size_t ibase = (size_t)b * 64 * HW + (size_t)y * H + x0;

    for (int r = tid; r < 8192; r += 256) {
        int which = r >> 12;
        int c = (r >> 6) & 63;
        int x = r & 63;
        S[which][c][x] = (which ? ta : ref)[ibase + (size_t)c * HW + x];
    }
    __syncthreads();
    if (tid < 64) {
        float s = 0.f;
#pragma unroll
        for (int c = 0; c < 64; ++c) s += (S[0][c][tid] > 0.95f) ? 0.f : 1.f;
        maskp[(size_t)b * HW + (size_t)y * H + x0 + tid] = s * (1.f / 64.f);
    }
    const size_t obase = ((size_t)b * HW + (size_t)y * H + x0) * 64;
    for (int r = tid; r < 8192; r += 256) {
        int which = r >> 12;
        int x = (r >> 6) & 63;
        int c = r & 63;
        (which ? tan : refn)[obase + (size_t)x * 64 + c] = __float2bfloat16(S[which][c][x]);
    }
}

// ---------------------------------------------------------------------------
// Fused per-window cross attention (R16-proven config).
template <bool HASATT>
__global__ __launch_bounds__(256, 4) void fused_attn_kernel(
    const __hip_bfloat16* __restrict__ refn,   // [NB][H][H][64] NHWC bf16
    const __hip_bfloat16* __restrict__ tan,
    const float* __restrict__ maskp,           // [NB][H][H] f32
    const __hip_bfloat16* __restrict__ WQ,     // [2 hl][64 co][64 ci] bf16 (hi used)
    const __hip_bfloat16* __restrict__ WK,
    const __hip_bfloat16* __restrict__ WV,
    const __hip_bfloat16* __restrict__ WPp,    // sigma-permuted ci axis
    const float* __restrict__ qb, const float* __restrict__ kb,
    const float* __restrict__ vb, const float* __restrict__ pb,
    const float* __restrict__ btab,  // [225][4]
    __hip_bfloat16* __restrict__ aligned,      // [NB][H][H][64] NHWC bf16
    __hip_bfloat16* __restrict__ attm,         // [NB][nWin][64][64] q-major bf16
    int H, int nWx, int nWin)
{
    __shared__ __align__(16) unsigned short PP[64 * 72];   // Q stage / attm transpose
    __shared__ __align__(16) unsigned short KH[64 * 72];   // K rows sigma-PERMUTED
    __shared__ __align__(16) unsigned short VT[64 * 72];   // V^T, true token cols
    __shared__ __align__(8) unsigned short BLB[900];       // bias * log2e, bf16
    __shared__ float MSK[64];

    const int HW = H * H;
    const int win = blockIdx.x;
    const int bb = blockIdx.y;
    const int wy = win / nWx, wx = win - wy * nWx;
    const int y0 = wy * 8, x0 = wx * 8;
    const int tid = threadIdx.x;
    const int w = __builtin_amdgcn_readfirstlane(tid >> 6);
    const int l = tid & 63;
    const int lq = l >> 4, lm = l & 15;

    for (int r = tid; r < 900; r += 256)
        BLB[r] = (unsigned short)f2bfbits(btab[r] * LOG2E);
    if (tid < 64)
        MSK[tid] = maskp[(size_t)bb * HW + (size_t)(y0 + (tid >> 3)) * H + x0 + (tid & 7)];

    // ---- phase A: Q/K/V projections (hi weights only)
    const int tokr = 16 * w + lm;
    const size_t prow = ((size_t)bb * HW
                         + (size_t)(y0 + (tokr >> 3)) * H + (x0 + (tokr & 7))) * 64;
    const unsigned short* xp = (const unsigned short*)refn + prow;
    const unsigned short* yp = (const unsigned short*)tan + prow;

    f32x4 aq[4], ak[4], av[4];
#pragma unroll
    for (int nt = 0; nt < 4; ++nt) {
        aq[nt] = (f32x4){0.f, 0.f, 0.f, 0.f};
        ak[nt] = (f32x4){0.f, 0.f, 0.f, 0.f};
        av[nt] = (f32x4){0.f, 0.f, 0.f, 0.f};
    }

#pragma unroll
    for (int stage = 0; stage < 2; ++stage) {
        const int cio = stage * 32 + lq * 8;
        short8 xa = *reinterpret_cast<const short8*>(xp + cio);
        short8 ya = *reinterpret_cast<const short8*>(yp + cio);
#pragma unroll
        for (int nt = 0; nt < 4; ++nt) {
            const int co = nt * 16 + lm;
            short8 bq = *reinterpret_cast<const short8*>(WQ + co * 64 + cio);
            aq[nt] = MFMA16(xa, bq, aq[nt], 0, 0, 0);
            short8 bk = *reinterpret_cast<const short8*>(WK + co * 64 + cio);
            ak[nt] = MFMA16(ya, bk, ak[nt], 0, 0, 0);
            short8 bv8 = *reinterpret_cast<const short8*>(WV + co * 64 + cio);
            av[nt] = MFMA16(ya, bv8, av[nt], 0, 0, 0);
        }
    }

    // ---- K (sigma-permuted rows) / V^T (true cols) epilogue + Q stage
#pragma unroll
    for (int nt = 0; nt < 4; ++nt) {
        const int co = nt * 16 + lm;
        const float kbv = kb[co], vbv = vb[co];
#pragma unroll
        for (int r = 0; r < 4; ++r) {
            const int tr = 16 * w + lq * 4 + r;                 // true token
            const int pr = 16 * (2 * (tr >> 5) + ((tr >> 2) & 1))
                         + 4 * ((tr >> 3) & 3) + (tr & 3);      // permuted row
            KH[pr * 72 + co] = (unsigned short)f2bfbits(ak[nt][r] + kbv);
            VT[co * 72 + tr] = (unsigned short)f2bfbits(av[nt][r] + vbv);
        }
    }
    {
        float mq_r[4];
#pragma unroll
        for (int r = 0; r < 4; ++r) mq_r[r] = MSK[16 * w + lq * 4 + r];
#pragma unroll
        for (int nt = 0; nt < 4; ++nt) {
            const float qbv = qb[nt * 16 + lm];
#pragma unroll
            for (int r = 0; r < 4; ++r)
                PP[(16 * w + lq * 4 + r) * 72 + nt * 16 + lm] =
                    (unsigned short)f2bfbits((aq[nt][r] * mq_r[r] + qbv) * 0.25f);
        }
    }
    __syncthreads();   // the ONLY barrier

    const short8 z8 = (short8){0, 0, 0, 0, 0, 0, 0, 0};
    const f32x4 zf = (f32x4){0.f, 0.f, 0.f, 0.f};
    short8 qfrag[4];
#pragma unroll
    for (int h = 0; h < 4; ++h)
        qfrag[h] = (lq < 2)
            ? *reinterpret_cast<const short8*>(&PP[(16 * w + lm) * 72 + 16 * h + lq * 8])
            : z8;

    const float mql = MSK[16 * w + lm] * LOG2E;
    const int qt = 16 * w + lm;
    const int qi = qt >> 3, qj = qt & 7;
    float m2[4][4];
    int bofs[4][4];
    int ktab[4][4];
#pragma unroll
    for (int nt = 0; nt < 4; ++nt)
#pragma unroll
        for (int r = 0; r < 4; ++r) {
            int kt = (nt >> 1) * 32 + lq * 8 + (nt & 1) * 4 + r;
            ktab[nt][r] = kt;
            m2[nt][r] = mql * MSK[kt];
            bofs[nt][r] = ((qi - (kt >> 3) + 7) * 15 + (qj - (kt & 7) + 7)) * 4;
        }

    float attAcc[HASATT ? 4 : 1][HASATT ? 4 : 1];
    if constexpr (HASATT) {
#pragma unroll
        for (int nt = 0; nt < 4; ++nt)
#pragma unroll
            for (int r = 0; r < 4; ++r) attAcc[nt][r] = 0.f;
    }
    f32x4 oacc[4];

#pragma unroll
    for (int hp = 0; hp < 2; ++hp) {
        unsigned int blv[4][4];
#pragma unroll
        for (int nt = 0; nt < 4; ++nt)
#pragma unroll
            for (int r = 0; r < 4; ++r)
                blv[nt][r] = *reinterpret_cast<const unsigned int*>(
                                 &BLB[bofs[nt][r] + hp * 2]);

        f32x4 s[2][4];
#pragma unroll
        for (int u = 0; u < 2; ++u) {
            const int h = hp * 2 + u;
#pragma unroll
            for (int nt = 0; nt < 4; ++nt) {
                short8 kf = (lq < 2)
                    ? *reinterpret_cast<const short8*>(
                          &KH[(nt * 16 + lm) * 72 + 16 * h + lq * 8])
                    : z8;
                s[u][nt] = MFMA16(kf, qfrag[h], zf, 0, 0, 0);   // C[k-pos][q]
            }
        }

        float p[2][4][4];
#pragma unroll
        for (int u = 0; u < 2; ++u)
#pragma unroll
            for (int nt = 0; nt < 4; ++nt)
#pragma unroll
                for (int r = 0; r < 4; ++r) {
                    float bias = u ? hi2f(blv[nt][r]) : lo2f(blv[nt][r]);
                    p[u][nt][r] = fmaf(s[u][nt][r], m2[nt][r], bias);
                }

        float inv[2];
#pragma unroll
        for (int u = 0; u < 2; ++u) {
            float a0 = fmaxf(p[u][0][0], p[u][0][1]);
            float a1 = fmaxf(p[u][0][2], p[u][0][3]);
            float a2 = fmaxf(p[u][1][0], p[u][1][1]);
            float a3 = fmaxf(p[u][1][2], p[u][1][3]);
            float a4 = fmaxf(p[u][2][0], p[u][2][1]);
            float a5 = fmaxf(p[u][2][2], p[u][2][3]);
            float a6 = fmaxf(p[u][3][0], p[u][3][1]);
            float a7 = fmaxf(p[u][3][2], p[u][3][3]);
            float b0 = fmaxf(a0, a1), b1 = fmaxf(a2, a3);
            float b2 = fmaxf(a4, a5), b3 = fmaxf(a6, a7);
            float m = fmaxf(fmaxf(b0, b1), fmaxf(b2, b3));
            m = fmaxf(m, __shfl_xor(m, 16));
            m = fmaxf(m, __shfl_xor(m, 32));
            float sm = 0.f;
#pragma unroll
            for (int nt = 0; nt < 4; ++nt)
#pragma unroll
                for (int r = 0; r < 4; ++r) {
                    p[u][nt][r] = exp2f(p[u][nt][r] - m);   // <= 1, bf16-safe
                    sm += p[u][nt][r];
                }
            sm += __shfl_xor(sm, 16);
            sm += __shfl_xor(sm, 32);
            inv[u] = 1.f / sm;
        }

        if constexpr (HASATT) {
#pragma unroll
            for (int u = 0; u < 2; ++u) {
                const float sc = 0.25f * inv[u];
#pragma unroll
                for (int nt = 0; nt < 4; ++nt)
#pragma unroll
                    for (int r = 0; r < 4; ++r)
                        attAcc[nt][r] = fmaf(sc, p[u][nt][r], attAcc[nt][r]);
            }
        }

#pragma unroll
        for (int u = 0; u < 2; ++u) {
            const int h = hp * 2 + u;
            short8 pb0, pb1;
#pragma unroll
            for (int j = 0; j < 8; ++j) {
                pb0[j] = f2bfbits(p[u][(j >> 2)][j & 3]);
                pb1[j] = f2bfbits(p[u][2 + (j >> 2)][j & 3]);
            }
            short8 vt0 = *reinterpret_cast<const short8*>(&VT[(16 * h + lm) * 72 + lq * 8]);
            short8 vt1 = *reinterpret_cast<const short8*>(&VT[(16 * h + lm) * 72 + 32 + lq * 8]);
            f32x4 o = MFMA16(vt0, pb0, zf, 0, 0, 0);   // C[d][q] (unnormalized)
            o = MFMA16(vt1, pb1, o, 0, 0, 0);
            oacc[h][0] = o[0] * inv[u]; oacc[h][1] = o[1] * inv[u];
            oacc[h][2] = o[2] * inv[u]; oacc[h][3] = o[3] * inv[u];
        }
    }

    if constexpr (HASATT) {
#pragma unroll
        for (int nt = 0; nt < 4; ++nt)
#pragma unroll
            for (int r = 0; r < 4; ++r)
                PP[(16 * w + lm) * 72 + ktab[nt][r]] =
                    (unsigned short)f2bfbits(attAcc[nt][r]);
        const int rr = 16 * w + (l >> 2), cb = (l & 3) * 16;
        short8 a0 = *reinterpret_cast<const short8*>(&PP[rr * 72 + cb]);
        short8 a1 = *reinterpret_cast<const short8*>(&PP[rr * 72 + cb + 8]);
        unsigned short* gp = (unsigned short*)attm
            + ((size_t)bb * nWin + win) * 4096 + (size_t)rr * 64 + cb;
        *reinterpret_cast<short8*>(gp) = a0;
        *reinterpret_cast<short8*>(gp + 8) = a1;
    }

    // ---- out-projection: O already in A-frag layout (WPp sigma-permuted, hi only)
    short8 oa0, oa1;
#pragma unroll
    for (int j = 0; j < 8; ++j) {
        oa0[j] = f2bfbits(oacc[(j >> 2)][j & 3]);
        oa1[j] = f2bfbits(oacc[2 + (j >> 2)][j & 3]);
    }
    f32x4 eo[4];
#pragma unroll
    for (int nt = 0; nt < 4; ++nt) {
        const int co = nt * 16 + lm;
        short8 wb0 = *reinterpret_cast<const short8*>(WPp + co * 64 + lq * 8);
        short8 wb1 = *reinterpret_cast<const short8*>(WPp + co * 64 + 32 + lq * 8);
        eo[nt] = MFMA16(oa0, wb0, zf, 0, 0, 0);
        eo[nt] = MFMA16(oa1, wb1, eo[nt], 0, 0, 0);
    }
    const size_t obase = (size_t)bb * HW * 64;
#pragma unroll
    for (int nt = 0; nt < 4; ++nt) {
        float pbv = pb[nt * 16 + lm];
#pragma unroll
        for (int r = 0; r < 4; ++r) {
            int tok = 16 * w + lq * 4 + r;
            aligned[obase + ((size_t)(y0 + (tok >> 3)) * H + (x0 + (tok & 7))) * 64
                    + nt * 16 + lm] = __float2bfloat16(eo[nt][r] + pbv);
        }
    }
}

// ---------------------------------------------------------------------------
// Attn-weight hi/lo split; WP (mat==3) gets the sigma ci-permutation.
__global__ __launch_bounds__(256) void wsplit_kernel(const float* __restrict__ qw,
                                                     const float* __restrict__ kw,
                                                     const float* __restrict__ vw,
                                                     const float* __restrict__ pw,
                                                     __hip_bfloat16* __restrict__ dst) {
    int idx = blockIdx.x * 256 + threadIdx.x;   // 49152 total
    int e = idx & 4095;
    int mat = (idx >> 12) & 3;
    int j = idx >> 14;
    int co = e >> 6, ci = e & 63;
    int src_ci = ci;
    if (mat == 3)
        src_ci = 16 * (2 * (ci >> 5) + ((ci >> 2) & 1)) + 4 * ((ci >> 3) & 3) + (ci & 3);
    const float* src = (mat == 0 ? qw : mat == 1 ? kw : mat == 2 ? vw : pw) + j * 4096;
    float v = src[co * 64 + src_ci];
    __hip_bfloat16 h = __float2bfloat16(v);
    dst[((size_t)j * 4 + mat) * 8192 + e] = h;
    dst[((size_t)j * 4 + mat) * 8192 + 4096 + e] = __float2bfloat16(v - __bfloat162float(h));
}

// ---------------------------------------------------------------------------
// atttrans as MFMA GEMM; attm bf16.
#define PSTR 4624
__global__ __launch_bounds__(256) void atttrans_kernel(
    const __hip_bfloat16* __restrict__ tan,    // [NB][H][H][64] NHWC bf16
    const __hip_bfloat16* __restrict__ attm,   // [NB][nWin][64][64] q-major bf16
    __hip_bfloat16* __restrict__ outw,         // [NB][H][H][64] NHWC bf16
    int H, int HW, int nWx16)
{
    __shared__ __align__(16) unsigned short AT[4608];        // [64 t][72 s]
    __shared__ __align__(16) unsigned short VTP[4 * PSTR];   // [p][64 c][72 s]

    const int tid = threadIdx.x;
    const int win = blockIdx.x;
    const int b = blockIdx.y;
    const int wh = win / nWx16, ww = win - wh * nWx16;
    const int w = __builtin_amdgcn_readfirstlane(tid >> 6);
    const int l = tid & 63;
    const int lq = l >> 4, lm = l & 15;

    const unsigned short* ap = (const unsigned short*)attm
        + ((size_t)b * nWx16 * nWx16 + win) * 4096;
    for (int s = tid; s < 512; s += 256) {
        short8 v = *reinterpret_cast<const short8*>(ap + s * 8);
        *reinterpret_cast<short8*>(&AT[(s >> 3) * 72 + (s & 7) * 8]) = v;
    }

    {
        const int yy = tid >> 4, xx = tid & 15;
        const int pp = ((yy & 1) << 1) | (xx & 1);
        const int s = ((yy >> 1) << 3) | (xx >> 1);
        const unsigned short* tp = (const unsigned short*)tan
            + ((size_t)b * HW + (size_t)(wh * 16 + yy) * H + (ww * 16 + xx)) * 64;
        unsigned short* vbp = &VTP[pp * PSTR + s];
#pragma unroll
        for (int oct = 0; oct < 8; ++oct) {
            short8 v = *reinterpret_cast<const short8*>(tp + oct * 8);
#pragma unroll
            for (int i = 0; i < 8; ++i) vbp[(oct * 8 + i) * 72] = (unsigned short)v[i];
        }
    }
    __syncthreads();

    f32x4 acc[4][4];
#pragma unroll
    for (int pp = 0; pp < 4; ++pp)
#pragma unroll
        for (int nt = 0; nt < 4; ++nt) acc[pp][nt] = (f32x4){0.f, 0.f, 0.f, 0.f};

#pragma unroll
    for (int kk = 0; kk < 2; ++kk) {
        short8 aA = *reinterpret_cast<const short8*>(
                        &AT[(16 * w + lm) * 72 + kk * 32 + lq * 8]);
#pragma unroll
        for (int pp = 0; pp < 4; ++pp) {
#pragma unroll
            for (int nt = 0; nt < 4; ++nt) {
                short8 bB = *reinterpret_cast<const short8*>(
                    &VTP[pp * PSTR + (nt * 16 + lm) * 72 + kk * 32 + lq * 8]);
                acc[pp][nt] = MFMA16(aA, bB, acc[pp][nt], 0, 0, 0);
            }
        }
    }

#pragma unroll
    for (int pp = 0; pp < 4; ++pp) {
        const int pi = pp >> 1, pj = pp & 1;
#pragma unroll
        for (int r = 0; r < 4; ++r) {
            const int t = 16 * w + lq * 4 + r;
            const int Y = wh * 16 + ((t >> 3) << 1) + pi;
            const int X = ww * 16 + ((t & 7) << 1) + pj;
            __hip_bfloat16* op = outw + ((size_t)b * HW + (size_t)Y * H + X) * 64;
#pragma unroll
            for (int nt = 0; nt < 4; ++nt)
                op[nt * 16 + lm] = __float2bfloat16(acc[pp][nt][r]);
        }
    }
}

// ---------------------------------------------------------------------------
// Conv weight transform (hi only used downstream; lo kept for layout parity)
__global__ __launch_bounds__(256) void wtrans_kernel(const float* __restrict__ src,
                                                     __hip_bfloat16* __restrict__ WH,
                                                     __hip_bfloat16* __restrict__ WL) {
    int idx = blockIdx.x * 256 + threadIdx.x;   // 110592 total
    int j = idx & 7;
    int t1 = idx >> 3;
    int co = t1 & 63;
    int t2 = t1 >> 6;
    int oct = t2 & 3;
    int t3 = t2 >> 2;
    int chunk = t3 % 6;
    int kykx = t3 / 6;
    int ci = chunk * 32 + oct * 8 + j;
    int ky = kykx / 3, kx = kykx % 3;
    float v = src[((co * 192 + ci) * 3 + ky) * 3 + kx];
    __hip_bfloat16 h = __float2bfloat16(v);
    WH[idx] = h;
    WL[idx] = __float2bfloat16(v - __bfloat162float(h));
}

// ---------------------------------------------------------------------------
// MFMA implicit-GEMM 3x3 conv — 512-thread / 8-wave blocks computing a
// [64co][8y][64x] tile. LDS single-buffer [10][66][40] = 52.8 KB ->
// 2 blocks/CU = 4 waves/SIMD (2x the previous TLP) with unchanged per-lane
// register budget. T14 issue-early/write-late staging, hi-only weights.
__global__ __launch_bounds__(512) void conv_mfma_kernel(
    const __hip_bfloat16* __restrict__ s0, const __hip_bfloat16* __restrict__ s1,
    const __hip_bfloat16* __restrict__ s2,
    const __hip_bfloat16* __restrict__ WHp,
    const float* __restrict__ bias,
    float* __restrict__ out,
    int H, int HW, int mode)
{
    __shared__ short I[10][66][40];

    const int tid = threadIdx.x;
    const int w   = tid >> 6;        // 0..7 : y row within tile
    const int l   = tid & 63;
    const int lq  = l >> 4;
    const int lm  = l & 15;
    const int x0  = blockIdx.x * 64;
    const int y0  = blockIdx.y * 8;
    const size_t zoff = (size_t)blockIdx.z * HW * 64;
    const short8 z8 = (short8){0, 0, 0, 0, 0, 0, 0, 0};

    f32x4 acc[4][4];
#pragma unroll
    for (int mt = 0; mt < 4; ++mt)
#pragma unroll
        for (int nt = 0; nt < 4; ++nt) acc[mt][nt] = (f32x4){0.f, 0.f, 0.f, 0.f};

    const short8* WH8 = reinterpret_cast<const short8*>(WHp);

    short8 st[6];                    // 2640 slots / 512 threads -> <=6 each
    const unsigned short* b0 = (const unsigned short*)s0;
    const unsigned short* b1 = (const unsigned short*)s1;
    const unsigned short* b2 = (const unsigned short*)s2;

    auto stage_load = [&](int chunk) {
        const unsigned short* src = (chunk < 2) ? b0 : (chunk < 4) ? b1 : b2;
        const int cib = (chunk & 1) * 32;
#pragma unroll
        for (int s = 0; s < 6; ++s) {
            int slot = tid + (s << 9);
            if (slot < 2640) {               // 10 rows x 66 x x 4 octs
                int oct = slot & 3;
                int xr = slot >> 2;
                int xi = xr % 66;
                int r = xr / 66;
                int gx = x0 - 1 + xi, gy = y0 - 1 + r;
                short8 v = z8;
                if (gx >= 0 && gx < H && gy >= 0 && gy < H)
                    v = *reinterpret_cast<const short8*>(
                            src + zoff + ((size_t)gy * H + gx) * 64 + cib + oct * 8);
                st[s] = v;
            }
        }
    };
    auto stage_write = [&]() {
#pragma unroll
        for (int s = 0; s < 6; ++s) {
            int slot = tid + (s << 9);
            if (slot < 2640) {
                int oct = slot & 3;
                int xr = slot >> 2;
                int xi = xr % 66;
                int r = xr / 66;
                *reinterpret_cast<short8*>(&I[r][xi][oct * 8]) = st[s];
            }
        }
    };

    stage_load(0);
    stage_write();
    __syncthreads();

    for (int chunk = 0; chunk < 6; ++chunk) {
        if (chunk < 5) stage_load(chunk + 1);   // issue early: drains under MFMAs
#pragma unroll
        for (int kk = 0; kk < 9; ++kk) {
            const int ky = kk / 3, kx = kk % 3;
            const int wbase = ((kk * 6 + chunk) * 4 + lq) * 64 + lm;
            short8 ah[4];
#pragma unroll
            for (int mt = 0; mt < 4; ++mt) ah[mt] = WH8[wbase + mt * 16];
#pragma unroll
            for (int nt = 0; nt < 4; ++nt) {
                short8 bfrag = *reinterpret_cast<const short8*>(
                                   &I[w + ky][nt * 16 + lm + kx][lq * 8]);
#pragma unroll
                for (int mt = 0; mt < 4; ++mt)
                    acc[mt][nt] = MFMA16(ah[mt], bfrag, acc[mt][nt], 0, 0, 0);
            }
        }
        if (chunk < 5) {
            __syncthreads();      // all waves done reading I
            stage_write();        // write-late: loads completed during compute
            __syncthreads();      // I ready for next chunk
        }
    }

    const int y = y0 + w;
#pragma unroll
    for (int mt = 0; mt < 4; ++mt) {
#pragma unroll
        for (int r = 0; r < 4; ++r) {
            const int co = mt * 16 + lq * 4 + r;
            const float bv = bias[co];
#pragma unroll
            for (int nt = 0; nt < 4; ++nt) {
                float v = acc[mt][nt][r] + bv;
                const int x = x0 + nt * 16 + lm;
                if (mode == 0) {
                    v = LRELU(v);
                    out[zoff + (size_t)co * HW + (size_t)y * H + x] = v;
                } else {
                    out[zoff + ((size_t)y * H + x) * 64 + co] = v;
                }
            }
        }
    }
}

// ---------------------------------------------------------------------------
// 2x bilinear upsample of lrelu(in); NHWC (unchanged)
template <typename T>
__global__ __launch_bounds__(256) void upsample_kernel(const T* __restrict__ in,
                                                       __hip_bfloat16* __restrict__ out,
                                                       int Hin, int total) {
    int idx = blockIdx.x * 256 + threadIdx.x;
    if (idx >= total) return;
    int c = idx & 63;
    int r1 = idx >> 6;
    int W2 = Hin * 2;
    int X = r1 % W2;
    int r2 = r1 / W2;
    int Y = r2 % W2;
    int b = r2 / W2;
    int y0 = Y >> 1, x0 = X >> 1;
    int ya = (Y & 1) ? y0 + 1 : y0 - 1;
    int xa = (X & 1) ? x0 + 1 : x0 - 1;
    ya = ya < 0 ? 0 : (ya >= Hin ? Hin - 1 : ya);
    xa = xa < 0 ? 0 : (xa >= Hin ? Hin - 1 : xa);
    const T* p = in + (size_t)b * Hin * Hin * 64;
    float v00 = LRELU(loadf(p + ((size_t)y0 * Hin + x0) * 64 + c));
    float v01 = LRELU(loadf(p + ((size_t)y0 * Hin + xa) * 64 + c));
    float v10 = LRELU(loadf(p + ((size_t)ya * Hin + x0) * 64 + c));
    float v11 = LRELU(loadf(p + ((size_t)ya * Hin + xa) * 64 + c));
    out[idx] = __float2bfloat16(0.5625f * v00 + 0.1875f * (v01 + v10) + 0.0625f * v11);
}

// ---------------------------------------------------------------------------
extern "C" void kernel_launch(void* const* d_in, const int* in_sizes, int n_in,
                              void* d_out, int out_size, void* d_ws, size_t ws_size,
                              hipStream_t stream) {
    const float* refs[3] = { (const float*)d_in[0], (const float*)d_in[1], (const float*)d_in[2] };
    const float* tas[3]  = { (const float*)d_in[3], (const float*)d_in[4], (const float*)d_in[5] };
    const float* q_w = (const float*)d_in[6];
    const float* q_b = (const float*)d_in[7];
    const float* k_w = (const float*)d_in[8];
    const float* k_b = (const float*)d_in[9];
    const float* v_w = (const float*)d_in[10];
    const float* v_b = (const float*)d_in[11];
    const float* p_w = (const float*)d_in[12];
    const float* p_b = (const float*)d_in[13];
    const float* btab = (const float*)d_in[14];
    const float* fc_w = (const float*)d_in[15];
    const float* fc_b = (const float*)d_in[16];

    const size_t WBYTES = 4ull * 221184 + 196608;
    const size_t BIG4 = 4ull * 65536 * 64 * 2;
    const size_t NEED4 = WBYTES + 4 * BIG4 + 4ull * 65536 * 4 + 4096;
    const int NB = (ws_size >= NEED4) ? 4 : 1;
    const size_t BIG = (size_t)NB * 65536 * 64 * 2;

    char* p = (char*)d_ws;
    __hip_bfloat16* WH0 = (__hip_bfloat16*)p;  p += 221184;
    __hip_bfloat16* WL0 = (__hip_bfloat16*)p;  p += 221184;
    __hip_bfloat16* WH1 = (__hip_bfloat16*)p;  p += 221184;
    __hip_bfloat16* WL1 = (__hip_bfloat16*)p;  p += 221184;
    __hip_bfloat16* WTA = (__hip_bfloat16*)p;  p += 196608;
    __hip_bfloat16* XRN = (__hip_bfloat16*)p;  p += BIG;
    __hip_bfloat16* XTN = (__hip_bfloat16*)p;  p += BIG;
    __hip_bfloat16* ALIGNED = (__hip_bfloat16*)p;  p += BIG;
    __hip_bfloat16* UPS     = (__hip_bfloat16*)p;  p += BIG;
    float* MASKP = (float*)p;  p += (size_t)NB * 65536 * 4;
    __hip_bfloat16* ATRANS = XRN;
    __hip_bfloat16 *ATTMA, *ATTMB;
    float* FEAT2;
    if (NB == 4) {
        ATTMA = (__hip_bfloat16*)d_out;                       // 2 MB
        ATTMB = (__hip_bfloat16*)((float*)d_out + 1048576);   // 8 MB
        FEAT2 = (float*)d_out + 5242880;                      // 16 MB
    } else {
        ATTMA = (__hip_bfloat16*)p;  p += (size_t)64 * 4096 * 2;
        ATTMB = (__hip_bfloat16*)p;  p += (size_t)256 * 4096 * 2;
        FEAT2 = (float*)p;           p += (size_t)16384 * 64 * 4;
    }

    wtrans_kernel<<<432, 256, 0, stream>>>(fc_w, WH0, WL0);
    wtrans_kernel<<<432, 256, 0, stream>>>(fc_w + 110592, WH1, WL1);
    wsplit_kernel<<<192, 256, 0, stream>>>(q_w, k_w, v_w, p_w, WTA);

    for (int b0 = 0; b0 < 4; b0 += NB) {
        const float* ref1 = refs[0] + (size_t)b0 * 64 * 65536;
        const float* ta1  = tas[0]  + (size_t)b0 * 64 * 65536;
        const float* ref2 = refs[1] + (size_t)b0 * 64 * 16384;
        const float* ta2  = tas[1]  + (size_t)b0 * 64 * 16384;
        const float* ref3 = refs[2] + (size_t)b0 * 64 * 4096;
        const float* ta3  = tas[2]  + (size_t)b0 * 64 * 4096;

        // ---- level j=2 (H=64, nWin=64)
        nhwc_kernel<<<dim3(64, NB), 256, 0, stream>>>(ref3, ta3, XRN, XTN, MASKP, 64, 4096);
        fused_attn_kernel<true><<<dim3(64, NB), 256, 0, stream>>>(
            XRN, XTN, MASKP,
            WTA + (2*4+0)*8192, WTA + (2*4+1)*8192, WTA + (2*4+2)*8192, WTA + (2*4+3)*8192,
            q_b + 2*64, k_b + 2*64, v_b + 2*64, p_b + 2*64,
            btab + 2*900, ALIGNED, ATTMA, 64, 8, 64);
        upsample_kernel<__hip_bfloat16><<<(NB * 64 * 16384) / 256, 256, 0, stream>>>(
            ALIGNED, UPS, 64, NB * 64 * 16384);

        // ---- level j=1 (H=128, nWin=256)
        nhwc_kernel<<<dim3(256, NB), 256, 0, stream>>>(ref2, ta2, XRN, XTN, MASKP, 128, 16384);
        fused_attn_kernel<true><<<dim3(256, NB), 256, 0, stream>>>(
            XRN, XTN, MASKP,
            WTA + (1*4+0)*8192, WTA + (1*4+1)*8192, WTA + (1*4+2)*8192, WTA + (1*4+3)*8192,
            q_b + 64, k_b + 64, v_b + 64, p_b + 64,
            btab + 900, ALIGNED, ATTMB, 128, 16, 256);
        atttrans_kernel<<<dim3(64, NB), 256, 0, stream>>>(
            XTN, ATTMA, ATRANS, 128, 16384, 8);
        conv_mfma_kernel<<<dim3(2, 16, NB), 512, 0, stream>>>(
            ALIGNED, UPS, ATRANS, WH1, fc_b + 64, FEAT2, 128, 16384, 1);
        upsample_kernel<float><<<(NB * 64 * 65536) / 256, 256, 0, stream>>>(
            FEAT2, UPS, 128, NB * 64 * 65536);

        // ---- level j=0 (H=256, nWin=1024)
        nhwc_kernel<<<dim3(1024, NB), 256, 0, stream>>>(ref1, ta1, XRN, XTN, MASKP, 256, 65536);
        fused_attn_kernel<false><<<dim3(1024, NB), 256, 0, stream>>>(
            XRN, XTN, MASKP,
            WTA + 0*8192, WTA + 1*8192, WTA + 2*8192, WTA + 3*8192,
            q_b, k_b, v_b, p_b,
            btab, ALIGNED, nullptr, 256, 32, 1024);
        atttrans_kernel<<<dim3(256, NB), 256, 0, stream>>>(
            XTN, ATTMB, ATRANS, 256, 65536, 16);
        conv_mfma_kernel<<<dim3(4, 32, NB), 512, 0, stream>>>(
            ALIGNED, UPS, ATRANS, WH0, fc_b,
            (float*)d_out + (size_t)b0 * 64 * 65536, 256, 65536, 0);
    }
}

// Round 23
// 408.003 us; speedup vs baseline: 1.0311x; 1.0311x over previous
//
#include <hip/hip_runtime.h>
#include <hip/hip_bf16.h>
#include <math.h>

#define LRELU(v) ((v) >= 0.f ? (v) : 0.1f * (v))
#define LOG2E 1.4426950408889634f

typedef __attribute__((ext_vector_type(8))) short short8;
typedef __attribute__((ext_vector_type(4))) float f32x4;

#define MFMA16 __builtin_amdgcn_mfma_f32_16x16x32_bf16

__device__ __forceinline__ float loadf(const float* p) { return *p; }
__device__ __forceinline__ float loadf(const __hip_bfloat16* p) { return __bfloat162float(*p); }
__device__ __forceinline__ short f2bfbits(float f) {
    __hip_bfloat16 h = __float2bfloat16(f);
    return *reinterpret_cast<short*>(&h);
}
__device__ __forceinline__ float bits2f(unsigned short u) {
    union { unsigned int i; float f; } x; x.i = ((unsigned int)u) << 16; return x.f;
}
__device__ __forceinline__ float lo2f(unsigned int v) {
    union { unsigned int i; float f; } x; x.i = v << 16; return x.f;
}
__device__ __forceinline__ float hi2f(unsigned int v) {
    union { unsigned int i; float f; } x; x.i = v & 0xFFFF0000u; return x.f;
}

// ---------------------------------------------------------------------------
// NCHW f32 -> NHWC bf16 transpose for ref+ta, + exact f32 overexposure mask.
__global__ __launch_bounds__(256) void nhwc_kernel(const float* __restrict__ ref,
                                                   const float* __restrict__ ta,
                                                   __hip_bfloat16* __restrict__ refn,
                                                   __hip_bfloat16* __restrict__ tan,
                                                   float* __restrict__ maskp,
                                                   int H, int HW) {
    __shared__ float S[2][64][67];
    const int tid = threadIdx.x;
    const int tile = blockIdx.x;
    const int b = blockIdx.y;
    const int tpr = H >> 6;
    const int y = tile / tpr;
    const int x0 = (tile - y * tpr) << 6;
    const size_t ibase = (size_t)b * 64 * HW + (size_t)y * H + x0;

    for (int r = tid; r < 8192; r += 256) {
        int which = r >> 12;
        int c = (r >> 6) & 63;
        int x = r & 63;
        S[which][c][x] = (which ? ta : ref)[ibase + (size_t)c * HW + x];
    }
    __syncthreads();
    if (tid < 64) {
        float s = 0.f;
#pragma unroll
        for (int c = 0; c < 64; ++c) s += (S[0][c][tid] > 0.95f) ? 0.f : 1.f;
        maskp[(size_t)b * HW + (size_t)y * H + x0 + tid] = s * (1.f / 64.f);
    }
    const size_t obase = ((size_t)b * HW + (size_t)y * H + x0) * 64;
    for (int r = tid; r < 8192; r += 256) {
        int which = r >> 12;
        int x = (r >> 6) & 63;
        int c = r & 63;
        (which ? tan : refn)[obase + (size_t)x * 64 + c] = __float2bfloat16(S[which][c][x]);
    }
}

// ---------------------------------------------------------------------------
// Fused per-window cross attention (R16-proven config).
template <bool HASATT>
__global__ __launch_bounds__(256, 4) void fused_attn_kernel(
    const __hip_bfloat16* __restrict__ refn,   // [NB][H][H][64] NHWC bf16
    const __hip_bfloat16* __restrict__ tan,
    const float* __restrict__ maskp,           // [NB][H][H] f32
    const __hip_bfloat16* __restrict__ WQ,     // [2 hl][64 co][64 ci] bf16 (hi used)
    const __hip_bfloat16* __restrict__ WK,
    const __hip_bfloat16* __restrict__ WV,
    const __hip_bfloat16* __restrict__ WPp,    // sigma-permuted ci axis
    const float* __restrict__ qb, const float* __restrict__ kb,
    const float* __restrict__ vb, const float* __restrict__ pb,
    const float* __restrict__ btab,  // [225][4]
    __hip_bfloat16* __restrict__ aligned,      // [NB][H][H][64] NHWC bf16
    __hip_bfloat16* __restrict__ attm,         // [NB][nWin][64][64] q-major bf16
    int H, int nWx, int nWin)
{
    __shared__ __align__(16) unsigned short PP[64 * 72];   // Q stage / attm transpose
    __shared__ __align__(16) unsigned short KH[64 * 72];   // K rows sigma-PERMUTED
    __shared__ __align__(16) unsigned short VT[64 * 72];   // V^T, true token cols
    __shared__ __align__(8) unsigned short BLB[900];       // bias * log2e, bf16
    __shared__ float MSK[64];

    const int HW = H * H;
    const int win = blockIdx.x;
    const int bb = blockIdx.y;
    const int wy = win / nWx, wx = win - wy * nWx;
    const int y0 = wy * 8, x0 = wx * 8;
    const int tid = threadIdx.x;
    const int w = __builtin_amdgcn_readfirstlane(tid >> 6);
    const int l = tid & 63;
    const int lq = l >> 4, lm = l & 15;

    for (int r = tid; r < 900; r += 256)
        BLB[r] = (unsigned short)f2bfbits(btab[r] * LOG2E);
    if (tid < 64)
        MSK[tid] = maskp[(size_t)bb * HW + (size_t)(y0 + (tid >> 3)) * H + x0 + (tid & 7)];

    // ---- phase A: Q/K/V projections (hi weights only)
    const int tokr = 16 * w + lm;
    const size_t prow = ((size_t)bb * HW
                         + (size_t)(y0 + (tokr >> 3)) * H + (x0 + (tokr & 7))) * 64;
    const unsigned short* xp = (const unsigned short*)refn + prow;
    const unsigned short* yp = (const unsigned short*)tan + prow;

    f32x4 aq[4], ak[4], av[4];
#pragma unroll
    for (int nt = 0; nt < 4; ++nt) {
        aq[nt] = (f32x4){0.f, 0.f, 0.f, 0.f};
        ak[nt] = (f32x4){0.f, 0.f, 0.f, 0.f};
        av[nt] = (f32x4){0.f, 0.f, 0.f, 0.f};
    }

#pragma unroll
    for (int stage = 0; stage < 2; ++stage) {
        const int cio = stage * 32 + lq * 8;
        short8 xa = *reinterpret_cast<const short8*>(xp + cio);
        short8 ya = *reinterpret_cast<const short8*>(yp + cio);
#pragma unroll
        for (int nt = 0; nt < 4; ++nt) {
            const int co = nt * 16 + lm;
            short8 bq = *reinterpret_cast<const short8*>(WQ + co * 64 + cio);
            aq[nt] = MFMA16(xa, bq, aq[nt], 0, 0, 0);
            short8 bk = *reinterpret_cast<const short8*>(WK + co * 64 + cio);
            ak[nt] = MFMA16(ya, bk, ak[nt], 0, 0, 0);
            short8 bv8 = *reinterpret_cast<const short8*>(WV + co * 64 + cio);
            av[nt] = MFMA16(ya, bv8, av[nt], 0, 0, 0);
        }
    }

    // ---- K (sigma-permuted rows) / V^T (true cols) epilogue + Q stage
#pragma unroll
    for (int nt = 0; nt < 4; ++nt) {
        const int co = nt * 16 + lm;
        const float kbv = kb[co], vbv = vb[co];
#pragma unroll
        for (int r = 0; r < 4; ++r) {
            const int tr = 16 * w + lq * 4 + r;                 // true token
            const int pr = 16 * (2 * (tr >> 5) + ((tr >> 2) & 1))
                         + 4 * ((tr >> 3) & 3) + (tr & 3);      // permuted row
            KH[pr * 72 + co] = (unsigned short)f2bfbits(ak[nt][r] + kbv);
            VT[co * 72 + tr] = (unsigned short)f2bfbits(av[nt][r] + vbv);
        }
    }
    {
        float mq_r[4];
#pragma unroll
        for (int r = 0; r < 4; ++r) mq_r[r] = MSK[16 * w + lq * 4 + r];
#pragma unroll
        for (int nt = 0; nt < 4; ++nt) {
            const float qbv = qb[nt * 16 + lm];
#pragma unroll
            for (int r = 0; r < 4; ++r)
                PP[(16 * w + lq * 4 + r) * 72 + nt * 16 + lm] =
                    (unsigned short)f2bfbits((aq[nt][r] * mq_r[r] + qbv) * 0.25f);
        }
    }
    __syncthreads();   // the ONLY barrier

    const short8 z8 = (short8){0, 0, 0, 0, 0, 0, 0, 0};
    const f32x4 zf = (f32x4){0.f, 0.f, 0.f, 0.f};
    short8 qfrag[4];
#pragma unroll
    for (int h = 0; h < 4; ++h)
        qfrag[h] = (lq < 2)
            ? *reinterpret_cast<const short8*>(&PP[(16 * w + lm) * 72 + 16 * h + lq * 8])
            : z8;

    const float mql = MSK[16 * w + lm] * LOG2E;
    const int qt = 16 * w + lm;
    const int qi = qt >> 3, qj = qt & 7;
    float m2[4][4];
    int bofs[4][4];
    int ktab[4][4];
#pragma unroll
    for (int nt = 0; nt < 4; ++nt)
#pragma unroll
        for (int r = 0; r < 4; ++r) {
            int kt = (nt >> 1) * 32 + lq * 8 + (nt & 1) * 4 + r;
            ktab[nt][r] = kt;
            m2[nt][r] = mql * MSK[kt];
            bofs[nt][r] = ((qi - (kt >> 3) + 7) * 15 + (qj - (kt & 7) + 7)) * 4;
        }

    float attAcc[HASATT ? 4 : 1][HASATT ? 4 : 1];
    if constexpr (HASATT) {
#pragma unroll
        for (int nt = 0; nt < 4; ++nt)
#pragma unroll
            for (int r = 0; r < 4; ++r) attAcc[nt][r] = 0.f;
    }
    f32x4 oacc[4];

#pragma unroll
    for (int hp = 0; hp < 2; ++hp) {
        unsigned int blv[4][4];
#pragma unroll
        for (int nt = 0; nt < 4; ++nt)
#pragma unroll
            for (int r = 0; r < 4; ++r)
                blv[nt][r] = *reinterpret_cast<const unsigned int*>(
                                 &BLB[bofs[nt][r] + hp * 2]);

        f32x4 s[2][4];
#pragma unroll
        for (int u = 0; u < 2; ++u) {
            const int h = hp * 2 + u;
#pragma unroll
            for (int nt = 0; nt < 4; ++nt) {
                short8 kf = (lq < 2)
                    ? *reinterpret_cast<const short8*>(
                          &KH[(nt * 16 + lm) * 72 + 16 * h + lq * 8])
                    : z8;
                s[u][nt] = MFMA16(kf, qfrag[h], zf, 0, 0, 0);   // C[k-pos][q]
            }
        }

        float p[2][4][4];
#pragma unroll
        for (int u = 0; u < 2; ++u)
#pragma unroll
            for (int nt = 0; nt < 4; ++nt)
#pragma unroll
                for (int r = 0; r < 4; ++r) {
                    float bias = u ? hi2f(blv[nt][r]) : lo2f(blv[nt][r]);
                    p[u][nt][r] = fmaf(s[u][nt][r], m2[nt][r], bias);
                }

        float inv[2];
#pragma unroll
        for (int u = 0; u < 2; ++u) {
            float a0 = fmaxf(p[u][0][0], p[u][0][1]);
            float a1 = fmaxf(p[u][0][2], p[u][0][3]);
            float a2 = fmaxf(p[u][1][0], p[u][1][1]);
            float a3 = fmaxf(p[u][1][2], p[u][1][3]);
            float a4 = fmaxf(p[u][2][0], p[u][2][1]);
            float a5 = fmaxf(p[u][2][2], p[u][2][3]);
            float a6 = fmaxf(p[u][3][0], p[u][3][1]);
            float a7 = fmaxf(p[u][3][2], p[u][3][3]);
            float b0 = fmaxf(a0, a1), b1 = fmaxf(a2, a3);
            float b2 = fmaxf(a4, a5), b3 = fmaxf(a6, a7);
            float m = fmaxf(fmaxf(b0, b1), fmaxf(b2, b3));
            m = fmaxf(m, __shfl_xor(m, 16));
            m = fmaxf(m, __shfl_xor(m, 32));
            float sm = 0.f;
#pragma unroll
            for (int nt = 0; nt < 4; ++nt)
#pragma unroll
                for (int r = 0; r < 4; ++r) {
                    p[u][nt][r] = exp2f(p[u][nt][r] - m);   // <= 1, bf16-safe
                    sm += p[u][nt][r];
                }
            sm += __shfl_xor(sm, 16);
            sm += __shfl_xor(sm, 32);
            inv[u] = 1.f / sm;
        }

        if constexpr (HASATT) {
#pragma unroll
            for (int u = 0; u < 2; ++u) {
                const float sc = 0.25f * inv[u];
#pragma unroll
                for (int nt = 0; nt < 4; ++nt)
#pragma unroll
                    for (int r = 0; r < 4; ++r)
                        attAcc[nt][r] = fmaf(sc, p[u][nt][r], attAcc[nt][r]);
            }
        }

#pragma unroll
        for (int u = 0; u < 2; ++u) {
            const int h = hp * 2 + u;
            short8 pb0, pb1;
#pragma unroll
            for (int j = 0; j < 8; ++j) {
                pb0[j] = f2bfbits(p[u][(j >> 2)][j & 3]);
                pb1[j] = f2bfbits(p[u][2 + (j >> 2)][j & 3]);
            }
            short8 vt0 = *reinterpret_cast<const short8*>(&VT[(16 * h + lm) * 72 + lq * 8]);
            short8 vt1 = *reinterpret_cast<const short8*>(&VT[(16 * h + lm) * 72 + 32 + lq * 8]);
            f32x4 o = MFMA16(vt0, pb0, zf, 0, 0, 0);   // C[d][q] (unnormalized)
            o = MFMA16(vt1, pb1, o, 0, 0, 0);
            oacc[h][0] = o[0] * inv[u]; oacc[h][1] = o[1] * inv[u];
            oacc[h][2] = o[2] * inv[u]; oacc[h][3] = o[3] * inv[u];
        }
    }

    if constexpr (HASATT) {
#pragma unroll
        for (int nt = 0; nt < 4; ++nt)
#pragma unroll
            for (int r = 0; r < 4; ++r)
                PP[(16 * w + lm) * 72 + ktab[nt][r]] =
                    (unsigned short)f2bfbits(attAcc[nt][r]);
        const int rr = 16 * w + (l >> 2), cb = (l & 3) * 16;
        short8 a0 = *reinterpret_cast<const short8*>(&PP[rr * 72 + cb]);
        short8 a1 = *reinterpret_cast<const short8*>(&PP[rr * 72 + cb + 8]);
        unsigned short* gp = (unsigned short*)attm
            + ((size_t)bb * nWin + win) * 4096 + (size_t)rr * 64 + cb;
        *reinterpret_cast<short8*>(gp) = a0;
        *reinterpret_cast<short8*>(gp + 8) = a1;
    }

    // ---- out-projection: O already in A-frag layout (WPp sigma-permuted, hi only)
    short8 oa0, oa1;
#pragma unroll
    for (int j = 0; j < 8; ++j) {
        oa0[j] = f2bfbits(oacc[(j >> 2)][j & 3]);
        oa1[j] = f2bfbits(oacc[2 + (j >> 2)][j & 3]);
    }
    f32x4 eo[4];
#pragma unroll
    for (int nt = 0; nt < 4; ++nt) {
        const int co = nt * 16 + lm;
        short8 wb0 = *reinterpret_cast<const short8*>(WPp + co * 64 + lq * 8);
        short8 wb1 = *reinterpret_cast<const short8*>(WPp + co * 64 + 32 + lq * 8);
        eo[nt] = MFMA16(oa0, wb0, zf, 0, 0, 0);
        eo[nt] = MFMA16(oa1, wb1, eo[nt], 0, 0, 0);
    }
    const size_t obase = (size_t)bb * HW * 64;
#pragma unroll
    for (int nt = 0; nt < 4; ++nt) {
        float pbv = pb[nt * 16 + lm];
#pragma unroll
        for (int r = 0; r < 4; ++r) {
            int tok = 16 * w + lq * 4 + r;
            aligned[obase + ((size_t)(y0 + (tok >> 3)) * H + (x0 + (tok & 7))) * 64
                    + nt * 16 + lm] = __float2bfloat16(eo[nt][r] + pbv);
        }
    }
}

// ---------------------------------------------------------------------------
// Attn-weight hi/lo split; WP (mat==3) gets the sigma ci-permutation.
__global__ __launch_bounds__(256) void wsplit_kernel(const float* __restrict__ qw,
                                                     const float* __restrict__ kw,
                                                     const float* __restrict__ vw,
                                                     const float* __restrict__ pw,
                                                     __hip_bfloat16* __restrict__ dst) {
    int idx = blockIdx.x * 256 + threadIdx.x;   // 49152 total
    int e = idx & 4095;
    int mat = (idx >> 12) & 3;
    int j = idx >> 14;
    int co = e >> 6, ci = e & 63;
    int src_ci = ci;
    if (mat == 3)
        src_ci = 16 * (2 * (ci >> 5) + ((ci >> 2) & 1)) + 4 * ((ci >> 3) & 3) + (ci & 3);
    const float* src = (mat == 0 ? qw : mat == 1 ? kw : mat == 2 ? vw : pw) + j * 4096;
    float v = src[co * 64 + src_ci];
    __hip_bfloat16 h = __float2bfloat16(v);
    dst[((size_t)j * 4 + mat) * 8192 + e] = h;
    dst[((size_t)j * 4 + mat) * 8192 + 4096 + e] = __float2bfloat16(v - __bfloat162float(h));
}

// ---------------------------------------------------------------------------
// atttrans as MFMA GEMM; attm bf16.
#define PSTR 4624
__global__ __launch_bounds__(256) void atttrans_kernel(
    const __hip_bfloat16* __restrict__ tan,    // [NB][H][H][64] NHWC bf16
    const __hip_bfloat16* __restrict__ attm,   // [NB][nWin][64][64] q-major bf16
    __hip_bfloat16* __restrict__ outw,         // [NB][H][H][64] NHWC bf16
    int H, int HW, int nWx16)
{
    __shared__ __align__(16) unsigned short AT[4608];        // [64 t][72 s]
    __shared__ __align__(16) unsigned short VTP[4 * PSTR];   // [p][64 c][72 s]

    const int tid = threadIdx.x;
    const int win = blockIdx.x;
    const int b = blockIdx.y;
    const int wh = win / nWx16, ww = win - wh * nWx16;
    const int w = __builtin_amdgcn_readfirstlane(tid >> 6);
    const int l = tid & 63;
    const int lq = l >> 4, lm = l & 15;

    const unsigned short* ap = (const unsigned short*)attm
        + ((size_t)b * nWx16 * nWx16 + win) * 4096;
    for (int s = tid; s < 512; s += 256) {
        short8 v = *reinterpret_cast<const short8*>(ap + s * 8);
        *reinterpret_cast<short8*>(&AT[(s >> 3) * 72 + (s & 7) * 8]) = v;
    }

    {
        const int yy = tid >> 4, xx = tid & 15;
        const int pp = ((yy & 1) << 1) | (xx & 1);
        const int s = ((yy >> 1) << 3) | (xx >> 1);
        const unsigned short* tp = (const unsigned short*)tan
            + ((size_t)b * HW + (size_t)(wh * 16 + yy) * H + (ww * 16 + xx)) * 64;
        unsigned short* vbp = &VTP[pp * PSTR + s];
#pragma unroll
        for (int oct = 0; oct < 8; ++oct) {
            short8 v = *reinterpret_cast<const short8*>(tp + oct * 8);
#pragma unroll
            for (int i = 0; i < 8; ++i) vbp[(oct * 8 + i) * 72] = (unsigned short)v[i];
        }
    }
    __syncthreads();

    f32x4 acc[4][4];
#pragma unroll
    for (int pp = 0; pp < 4; ++pp)
#pragma unroll
        for (int nt = 0; nt < 4; ++nt) acc[pp][nt] = (f32x4){0.f, 0.f, 0.f, 0.f};

#pragma unroll
    for (int kk = 0; kk < 2; ++kk) {
        short8 aA = *reinterpret_cast<const short8*>(
                        &AT[(16 * w + lm) * 72 + kk * 32 + lq * 8]);
#pragma unroll
        for (int pp = 0; pp < 4; ++pp) {
#pragma unroll
            for (int nt = 0; nt < 4; ++nt) {
                short8 bB = *reinterpret_cast<const short8*>(
                    &VTP[pp * PSTR + (nt * 16 + lm) * 72 + kk * 32 + lq * 8]);
                acc[pp][nt] = MFMA16(aA, bB, acc[pp][nt], 0, 0, 0);
            }
        }
    }

#pragma unroll
    for (int pp = 0; pp < 4; ++pp) {
        const int pi = pp >> 1, pj = pp & 1;
#pragma unroll
        for (int r = 0; r < 4; ++r) {
            const int t = 16 * w + lq * 4 + r;
            const int Y = wh * 16 + ((t >> 3) << 1) + pi;
            const int X = ww * 16 + ((t & 7) << 1) + pj;
            __hip_bfloat16* op = outw + ((size_t)b * HW + (size_t)Y * H + X) * 64;
#pragma unroll
            for (int nt = 0; nt < 4; ++nt)
                op[nt * 16 + lm] = __float2bfloat16(acc[pp][nt][r]);
        }
    }
}

// ---------------------------------------------------------------------------
// Conv weight transform (hi only used downstream; lo kept for layout parity)
__global__ __launch_bounds__(256) void wtrans_kernel(const float* __restrict__ src,
                                                     __hip_bfloat16* __restrict__ WH,
                                                     __hip_bfloat16* __restrict__ WL) {
    int idx = blockIdx.x * 256 + threadIdx.x;   // 110592 total
    int j = idx & 7;
    int t1 = idx >> 3;
    int co = t1 & 63;
    int t2 = t1 >> 6;
    int oct = t2 & 3;
    int t3 = t2 >> 2;
    int chunk = t3 % 6;
    int kykx = t3 / 6;
    int ci = chunk * 32 + oct * 8 + j;
    int ky = kykx / 3, kx = kykx % 3;
    float v = src[((co * 192 + ci) * 3 + ky) * 3 + kx];
    __hip_bfloat16 h = __float2bfloat16(v);
    WH[idx] = h;
    WL[idx] = __float2bfloat16(v - __bfloat162float(h));
}

// ---------------------------------------------------------------------------
// MFMA implicit-GEMM 3x3 conv — hi-only bf16 weights, DOUBLE-BUFFERED LDS
// (best-measured config, R21: 105-107 us @ j0).
__global__ __launch_bounds__(256) void conv_mfma_kernel(
    const __hip_bfloat16* __restrict__ s0, const __hip_bfloat16* __restrict__ s1,
    const __hip_bfloat16* __restrict__ s2,
    const __hip_bfloat16* __restrict__ WHp,
    const float* __restrict__ bias,
    float* __restrict__ out,
    int H, int HW, int mode)
{
    __shared__ short I[2][6][66][40];

    const int tid = threadIdx.x;
    const int w   = tid >> 6;
    const int l   = tid & 63;
    const int lq  = l >> 4;
    const int lm  = l & 15;
    const int x0  = blockIdx.x * 64;
    const int y0  = blockIdx.y * 4;
    const size_t zoff = (size_t)blockIdx.z * HW * 64;
    const short8 z8 = (short8){0, 0, 0, 0, 0, 0, 0, 0};

    f32x4 acc[4][4];
#pragma unroll
    for (int mt = 0; mt < 4; ++mt)
#pragma unroll
        for (int nt = 0; nt < 4; ++nt) acc[mt][nt] = (f32x4){0.f, 0.f, 0.f, 0.f};

    const short8* WH8 = reinterpret_cast<const short8*>(WHp);

    short8 st[7];
    const unsigned short* b0 = (const unsigned short*)s0;
    const unsigned short* b1 = (const unsigned short*)s1;
    const unsigned short* b2 = (const unsigned short*)s2;

    auto stage_load = [&](int chunk) {
        const unsigned short* src = (chunk < 2) ? b0 : (chunk < 4) ? b1 : b2;
        const int cib = (chunk & 1) * 32;
#pragma unroll
        for (int s = 0; s < 7; ++s) {
            int slot = tid + (s << 8);
            if (slot < 1584) {
                int oct = slot & 3;
                int xr = slot >> 2;
                int xi = xr % 66;
                int r = xr / 66;
                int gx = x0 - 1 + xi, gy = y0 - 1 + r;
                short8 v = z8;
                if (gx >= 0 && gx < H && gy >= 0 && gy < H)
                    v = *reinterpret_cast<const short8*>(
                            src + zoff + ((size_t)gy * H + gx) * 64 + cib + oct * 8);
                st[s] = v;
            }
        }
    };
    auto stage_write = [&](int buf) {
#pragma unroll
        for (int s = 0; s < 7; ++s) {
            int slot = tid + (s << 8);
            if (slot < 1584) {
                int oct = slot & 3;
                int xr = slot >> 2;
                int xi = xr % 66;
                int r = xr / 66;
                *reinterpret_cast<short8*>(&I[buf][r][xi][oct * 8]) = st[s];
            }
        }
    };

    stage_load(0);
    stage_write(0);
    __syncthreads();

    for (int chunk = 0; chunk < 6; ++chunk) {
        const int buf = chunk & 1;
        if (chunk < 5) stage_load(chunk + 1);   // issue early: drains under MFMAs
#pragma unroll
        for (int kk = 0; kk < 9; ++kk) {
            const int ky = kk / 3, kx = kk % 3;
            const int wbase = ((kk * 6 + chunk) * 4 + lq) * 64 + lm;
            short8 ah[4];
#pragma unroll
            for (int mt = 0; mt < 4; ++mt) ah[mt] = WH8[wbase + mt * 16];
#pragma unroll
            for (int nt = 0; nt < 4; ++nt) {
                short8 bfrag = *reinterpret_cast<const short8*>(
                                   &I[buf][w + ky][nt * 16 + lm + kx][lq * 8]);
#pragma unroll
                for (int mt = 0; mt < 4; ++mt)
                    acc[mt][nt] = MFMA16(ah[mt], bfrag, acc[mt][nt], 0, 0, 0);
            }
        }
        if (chunk < 5) {
            stage_write(buf ^ 1);   // safe: chunk-1 readers passed last barrier
            __syncthreads();        // ONE barrier per chunk
        }
    }

    const int y = y0 + w;
#pragma unroll
    for (int mt = 0; mt < 4; ++mt) {
#pragma unroll
        for (int r = 0; r < 4; ++r) {
            const int co = mt * 16 + lq * 4 + r;
            const float bv = bias[co];
#pragma unroll
            for (int nt = 0; nt < 4; ++nt) {
                float v = acc[mt][nt][r] + bv;
                const int x = x0 + nt * 16 + lm;
                if (mode == 0) {
                    v = LRELU(v);
                    out[zoff + (size_t)co * HW + (size_t)y * H + x] = v;
                } else {
                    out[zoff + ((size_t)y * H + x) * 64 + co] = v;
                }
            }
        }
    }
}

// ---------------------------------------------------------------------------
// 2x bilinear upsample of lrelu(in); NHWC (unchanged)
template <typename T>
__global__ __launch_bounds__(256) void upsample_kernel(const T* __restrict__ in,
                                                       __hip_bfloat16* __restrict__ out,
                                                       int Hin, int total) {
    int idx = blockIdx.x * 256 + threadIdx.x;
    if (idx >= total) return;
    int c = idx & 63;
    int r1 = idx >> 6;
    int W2 = Hin * 2;
    int X = r1 % W2;
    int r2 = r1 / W2;
    int Y = r2 % W2;
    int b = r2 / W2;
    int y0 = Y >> 1, x0 = X >> 1;
    int ya = (Y & 1) ? y0 + 1 : y0 - 1;
    int xa = (X & 1) ? x0 + 1 : x0 - 1;
    ya = ya < 0 ? 0 : (ya >= Hin ? Hin - 1 : ya);
    xa = xa < 0 ? 0 : (xa >= Hin ? Hin - 1 : xa);
    const T* p = in + (size_t)b * Hin * Hin * 64;
    float v00 = LRELU(loadf(p + ((size_t)y0 * Hin + x0) * 64 + c));
    float v01 = LRELU(loadf(p + ((size_t)y0 * Hin + xa) * 64 + c));
    float v10 = LRELU(loadf(p + ((size_t)ya * Hin + x0) * 64 + c));
    float v11 = LRELU(loadf(p + ((size_t)ya * Hin + xa) * 64 + c));
    out[idx] = __float2bfloat16(0.5625f * v00 + 0.1875f * (v01 + v10) + 0.0625f * v11);
}

// ---------------------------------------------------------------------------
extern "C" void kernel_launch(void* const* d_in, const int* in_sizes, int n_in,
                              void* d_out, int out_size, void* d_ws, size_t ws_size,
                              hipStream_t stream) {
    const float* refs[3] = { (const float*)d_in[0], (const float*)d_in[1], (const float*)d_in[2] };
    const float* tas[3]  = { (const float*)d_in[3], (const float*)d_in[4], (const float*)d_in[5] };
    const float* q_w = (const float*)d_in[6];
    const float* q_b = (const float*)d_in[7];
    const float* k_w = (const float*)d_in[8];
    const float* k_b = (const float*)d_in[9];
    const float* v_w = (const float*)d_in[10];
    const float* v_b = (const float*)d_in[11];
    const float* p_w = (const float*)d_in[12];
    const float* p_b = (const float*)d_in[13];
    const float* btab = (const float*)d_in[14];
    const float* fc_w = (const float*)d_in[15];
    const float* fc_b = (const float*)d_in[16];

    const size_t WBYTES = 4ull * 221184 + 196608;
    const size_t BIG4 = 4ull * 65536 * 64 * 2;
    const size_t NEED4 = WBYTES + 4 * BIG4 + 4ull * 65536 * 4 + 4096;
    const int NB = (ws_size >= NEED4) ? 4 : 1;
    const size_t BIG = (size_t)NB * 65536 * 64 * 2;

    char* p = (char*)d_ws;
    __hip_bfloat16* WH0 = (__hip_bfloat16*)p;  p += 221184;
    __hip_bfloat16* WL0 = (__hip_bfloat16*)p;  p += 221184;
    __hip_bfloat16* WH1 = (__hip_bfloat16*)p;  p += 221184;
    __hip_bfloat16* WL1 = (__hip_bfloat16*)p;  p += 221184;
    __hip_bfloat16* WTA = (__hip_bfloat16*)p;  p += 196608;
    __hip_bfloat16* XRN = (__hip_bfloat16*)p;  p += BIG;
    __hip_bfloat16* XTN = (__hip_bfloat16*)p;  p += BIG;
    __hip_bfloat16* ALIGNED = (__hip_bfloat16*)p;  p += BIG;
    __hip_bfloat16* UPS     = (__hip_bfloat16*)p;  p += BIG;
    float* MASKP = (float*)p;  p += (size_t)NB * 65536 * 4;
    __hip_bfloat16* ATRANS = XRN;
    __hip_bfloat16 *ATTMA, *ATTMB;
    float* FEAT2;
    if (NB == 4) {
        ATTMA = (__hip_bfloat16*)d_out;                       // 2 MB
        ATTMB = (__hip_bfloat16*)((float*)d_out + 1048576);   // 8 MB
        FEAT2 = (float*)d_out + 5242880;                      // 16 MB
    } else {
        ATTMA = (__hip_bfloat16*)p;  p += (size_t)64 * 4096 * 2;
        ATTMB = (__hip_bfloat16*)p;  p += (size_t)256 * 4096 * 2;
        FEAT2 = (float*)p;           p += (size_t)16384 * 64 * 4;
    }

    wtrans_kernel<<<432, 256, 0, stream>>>(fc_w, WH0, WL0);
    wtrans_kernel<<<432, 256, 0, stream>>>(fc_w + 110592, WH1, WL1);
    wsplit_kernel<<<192, 256, 0, stream>>>(q_w, k_w, v_w, p_w, WTA);

    for (int b0 = 0; b0 < 4; b0 += NB) {
        const float* ref1 = refs[0] + (size_t)b0 * 64 * 65536;
        const float* ta1  = tas[0]  + (size_t)b0 * 64 * 65536;
        const float* ref2 = refs[1] + (size_t)b0 * 64 * 16384;
        const float* ta2  = tas[1]  + (size_t)b0 * 64 * 16384;
        const float* ref3 = refs[2] + (size_t)b0 * 64 * 4096;
        const float* ta3  = tas[2]  + (size_t)b0 * 64 * 4096;

        // ---- level j=2 (H=64, nWin=64)
        nhwc_kernel<<<dim3(64, NB), 256, 0, stream>>>(ref3, ta3, XRN, XTN, MASKP, 64, 4096);
        fused_attn_kernel<true><<<dim3(64, NB), 256, 0, stream>>>(
            XRN, XTN, MASKP,
            WTA + (2*4+0)*8192, WTA + (2*4+1)*8192, WTA + (2*4+2)*8192, WTA + (2*4+3)*8192,
            q_b + 2*64, k_b + 2*64, v_b + 2*64, p_b + 2*64,
            btab + 2*900, ALIGNED, ATTMA, 64, 8, 64);
        upsample_kernel<__hip_bfloat16><<<(NB * 64 * 16384) / 256, 256, 0, stream>>>(
            ALIGNED, UPS, 64, NB * 64 * 16384);

        // ---- level j=1 (H=128, nWin=256)
        nhwc_kernel<<<dim3(256, NB), 256, 0, stream>>>(ref2, ta2, XRN, XTN, MASKP, 128, 16384);
        fused_attn_kernel<true><<<dim3(256, NB), 256, 0, stream>>>(
            XRN, XTN, MASKP,
            WTA + (1*4+0)*8192, WTA + (1*4+1)*8192, WTA + (1*4+2)*8192, WTA + (1*4+3)*8192,
            q_b + 64, k_b + 64, v_b + 64, p_b + 64,
            btab + 900, ALIGNED, ATTMB, 128, 16, 256);
        atttrans_kernel<<<dim3(64, NB), 256, 0, stream>>>(
            XTN, ATTMA, ATRANS, 128, 16384, 8);
        conv_mfma_kernel<<<dim3(2, 32, NB), 256, 0, stream>>>(
            ALIGNED, UPS, ATRANS, WH1, fc_b + 64, FEAT2, 128, 16384, 1);
        upsample_kernel<float><<<(NB * 64 * 65536) / 256, 256, 0, stream>>>(
            FEAT2, UPS, 128, NB * 64 * 65536);

        // ---- level j=0 (H=256, nWin=1024)
        nhwc_kernel<<<dim3(1024, NB), 256, 0, stream>>>(ref1, ta1, XRN, XTN, MASKP, 256, 65536);
        fused_attn_kernel<false><<<dim3(1024, NB), 256, 0, stream>>>(
            XRN, XTN, MASKP,
            WTA + 0*8192, WTA + 1*8192, WTA + 2*8192, WTA + 3*8192,
            q_b, k_b, v_b, p_b,
            btab, ALIGNED, nullptr, 256, 32, 1024);
        atttrans_kernel<<<dim3(256, NB), 256, 0, stream>>>(
            XTN, ATTMB, ATRANS, 256, 65536, 16);
        conv_mfma_kernel<<<dim3(4, 64, NB), 256, 0, stream>>>(
            ALIGNED, UPS, ATRANS, WH0, fc_b,
            (float*)d_out + (size_t)b0 * 64 * 65536, 256, 65536, 0);
    }
}